// Round 22
// baseline (311.603 us; speedup 1.0000x reference)
//
#include <hip/hip_runtime.h>

#define SS 2048
#define DD 1024
#define HH 16
#define HD 64
#define MM 8192   // B*S

typedef unsigned short ushort_t;
typedef __attribute__((ext_vector_type(8))) short short8;
typedef __attribute__((ext_vector_type(4))) float f32x4;
typedef __attribute__((ext_vector_type(4))) unsigned short us4;
typedef __attribute__((ext_vector_type(8))) unsigned short us8;

__device__ __forceinline__ ushort_t f2bf(float f) {
    union { float f; unsigned u; } x; x.f = f;
    unsigned r = x.u + 0x7fffu + ((x.u >> 16) & 1u);
    return (ushort_t)(r >> 16);
}
__device__ __forceinline__ float bf2f(ushort_t h) {
    union { unsigned u; float f; } x; x.u = ((unsigned)h) << 16; return x.f;
}
// [hi16(b)<<16 | hi16(a)]: truncating bf16 pack of two fp32, one v_perm
__device__ __forceinline__ unsigned pack_bf2(float a, float b) {
    union { float f; unsigned u; } x, y; x.f = a; y.f = b;
    return __builtin_amdgcn_perm(y.u, x.u, 0x07060302u);
}

// async global->LDS, 16B per lane. LDS dst = wave-uniform base + lane*16.
__device__ __forceinline__ void async16(const void* g, void* l) {
    __builtin_amdgcn_global_load_lds(
        (const __attribute__((address_space(1))) unsigned int*)g,
        (__attribute__((address_space(3))) unsigned int*)l, 16, 0, 0);
}

// ---------------- cvt fp32 -> bf16: q,k,v (8M each) + 4 weights (1M each) ----
// Dedicated memory-bound pass (r0/r9 proved in-GEMM variants lose more).
// Flat 14336-block launch (r18's grid-stride regressed +9us).
__global__ void cvt_all(const float* __restrict__ q, const float* __restrict__ k,
                        const float* __restrict__ v, const float* __restrict__ wq,
                        const float* __restrict__ wk, const float* __restrict__ wv,
                        const float* __restrict__ wo, ushort_t* __restrict__ qbf,
                        ushort_t* __restrict__ kbf, ushort_t* __restrict__ vbf,
                        ushort_t* __restrict__ wbf) {
    long i = ((long)blockIdx.x * 256 + threadIdx.x) * 8;
    const float* src; ushort_t* dst;
    if (i < (3l << 23)) {
        int s = (int)(i >> 23);
        long off = i & ((1l << 23) - 1);
        src = ((s == 0) ? q : (s == 1) ? k : v) + off;
        dst = ((s == 0) ? qbf : (s == 1) ? kbf : vbf) + off;
    } else {
        long j = i - (3l << 23);
        int s = (int)(j >> 20);
        src = ((s == 0) ? wq : (s == 1) ? wk : (s == 2) ? wv : wo) + (j & 1048575);
        dst = wbf + j;
    }
    float4 f0 = *(const float4*)src;
    float4 f1 = *(const float4*)(src + 4);
    us8 o;
    o[0] = f2bf(f0.x); o[1] = f2bf(f0.y); o[2] = f2bf(f0.z); o[3] = f2bf(f0.w);
    o[4] = f2bf(f1.x); o[5] = f2bf(f1.y); o[6] = f2bf(f1.z); o[7] = f2bf(f1.w);
    *(us8*)dst = o;
}

// ---------------- epilogue store --------------------------------------------
// mode 0: bf16 [B,H,S,HD]; mode 1: bf16 [B,H,HD,S] with key-permuted S;
// mode 2: fp32 row-major [M,D]
__device__ __forceinline__ void epi_store(int row, int col, float vf, int mode,
                                          void* Yv) {
    if (mode == 2) {
        ((float*)Yv)[(size_t)row * DD + col] = vf;
    } else {
        ushort_t vh = f2bf(vf);
        int b = row >> 11, s = row & 2047;
        int h = col >> 6,  hd = col & 63;
        if (mode == 0) {
            ((ushort_t*)Yv)[(((size_t)b * HH + h) * SS + s) * HD + hd] = vh;
        } else {
            // key k = s%64 stored at pos (k&15)*4 + (k>>4)&3
            int sp = (s & ~63) | (((s & 15) << 2) | ((s >> 4) & 3));
            ((ushort_t*)Yv)[(((size_t)b * HH + h) * HD + hd) * SS + sp] = vh;
        }
    }
}

// ---------------- shared GEMM body: 128^2, 8 waves, 3-buf T4 (session best) --
// r12/r14-verified: proj3f 89us, MfmaUtil 23.7, occ 51%. Per-wave 64x32
// (acc[4][2]), 3 LDS buffers, prefetch depth 2, vmcnt 4/2/0, 1 A + 1 B
// staging granule per thread, (r&3) granule XOR.
// CLOSED variants (all measured worse): 2-buf/32KB (r13: +8us); deepened XOR
// (r15: +8us); 256-row tile (r2); fp32-A staging (r9); 4-wave blocks (+12us).
__device__ __forceinline__ void gemm128_body(const ushort_t* __restrict__ A,
                                             const ushort_t* __restrict__ Bw,
                                             int m0, int n0, int mode, void* Y,
                                             ushort_t (*As)[128 * 32],
                                             ushort_t (*Bs)[128 * 32]) {
    int tid = threadIdx.x;
    int w = tid >> 6, lane = tid & 63;
    int l16 = lane & 15, quad = lane >> 4;
    int wm = (w >> 2) * 64, wn = (w & 3) * 32;   // 2M x 4N waves, 64x32 each

    f32x4 acc[4][2];
    #pragma unroll
    for (int i = 0; i < 4; ++i)
        #pragma unroll
        for (int j = 0; j < 2; ++j) acc[i][j] = (f32x4){0.f, 0.f, 0.f, 0.f};

    int r0 = tid >> 2, j0 = ((tid & 3) ^ (r0 & 3)) * 8;
    int swA = (quad ^ (l16 & 3)) * 8;

    const ushort_t* Ar0 = A  + (size_t)(m0 + r0) * DD + j0;
    const ushort_t* Br0 = Bw + (size_t)(n0 + r0) * DD + j0;
    int ldsb = w * 64 * 8;                        // wave-uniform base

    // prologue: stage k=0 -> buf0, k=1 -> buf1 (4 loads outstanding)
    async16(Ar0,      &As[0][ldsb]);
    async16(Br0,      &Bs[0][ldsb]);
    async16(Ar0 + 32, &As[1][ldsb]);
    async16(Br0 + 32, &Bs[1][ldsb]);

    int c = 0, c2 = 2;   // compute buffer, stage-target buffer (= c+2 mod 3)
    for (int kk = 0; kk < 32; ++kk) {
        __builtin_amdgcn_s_barrier();          // iter kk-1 readers of buf c2 done
        if (kk < 30) {
            int k2 = (kk + 2) * 32;
            async16(Ar0 + k2, &As[c2][ldsb]);
            async16(Br0 + k2, &Bs[c2][ldsb]);
            asm volatile("s_waitcnt vmcnt(4)" ::: "memory");   // stage(kk) landed
        } else if (kk == 30) {
            asm volatile("s_waitcnt vmcnt(2)" ::: "memory");
        } else {
            asm volatile("s_waitcnt vmcnt(0)" ::: "memory");
        }
        __builtin_amdgcn_s_barrier();          // ALL waves' stage(kk) landed
        __builtin_amdgcn_sched_barrier(0);

        short8 af[4], bfr[2];
        #pragma unroll
        for (int t = 0; t < 4; ++t)
            af[t] = *(const short8*)&As[c][(wm + t * 16 + l16) * 32 + swA];
        #pragma unroll
        for (int t = 0; t < 2; ++t)
            bfr[t] = *(const short8*)&Bs[c][(wn + t * 16 + l16) * 32 + swA];
        #pragma unroll
        for (int mt = 0; mt < 4; ++mt)
            #pragma unroll
            for (int nt = 0; nt < 2; ++nt)
                acc[mt][nt] = __builtin_amdgcn_mfma_f32_16x16x32_bf16(af[mt], bfr[nt], acc[mt][nt], 0, 0, 0);

        c  = (c  == 2) ? 0 : c  + 1;
        c2 = (c2 == 2) ? 0 : c2 + 1;
    }

    #pragma unroll
    for (int mt = 0; mt < 4; ++mt)
        #pragma unroll
        for (int r = 0; r < 4; ++r) {
            int row = m0 + wm + mt * 16 + quad * 4 + r;
            #pragma unroll
            for (int nt = 0; nt < 2; ++nt)
                epi_store(row, n0 + wn + nt * 16 + l16, acc[mt][nt][r], mode, Y);
        }
}

// ---------------- fused projections ------------------------------------------
__global__ __launch_bounds__(512) void proj3f(const ushort_t* __restrict__ qbf,
                                              const ushort_t* __restrict__ kbf,
                                              const ushort_t* __restrict__ vbf,
                                              const ushort_t* __restrict__ Wall,
                                              ushort_t* __restrict__ xq,
                                              ushort_t* __restrict__ xk,
                                              ushort_t* __restrict__ xvT) {
    __shared__ __align__(16) ushort_t As[3][128 * 32];
    __shared__ __align__(16) ushort_t Bs[3][128 * 32];
    int mat   = (int)(blockIdx.x >> 9);
    int inner = (int)(blockIdx.x & 511);
    int m0 = (inner & 63) * 128;     // XCD swizzle: A-panel sharers on one XCD
    int n0 = (inner >> 6) * 128;
    const ushort_t* A  = (mat == 0) ? qbf : (mat == 1) ? kbf : vbf;
    const ushort_t* Bw = Wall + ((size_t)mat << 20);
    void* Y = (mat == 0) ? (void*)xq : (mat == 1) ? (void*)xk : (void*)xvT;
    gemm128_body(A, Bw, m0, n0, (mat == 2) ? 1 : 0, Y, As, Bs);
}

// ---------------- output GEMM ------------------------------------------------
__global__ __launch_bounds__(512) void out_gemm(const ushort_t* __restrict__ Abf,
                                                const ushort_t* __restrict__ Bw,
                                                float* __restrict__ Y) {
    __shared__ __align__(16) ushort_t As[3][128 * 32];
    __shared__ __align__(16) ushort_t Bs[3][128 * 32];
    int m0 = (int)(blockIdx.x & 63) * 128;   // XCD swizzle
    int n0 = (int)(blockIdx.x >> 6) * 128;
    gemm128_body(Abf, Bw, m0, n0, 2, (void*)Y, As, Bs);
}

// ---------------- attn per-tile compute body ---------------------------------
// Verified body (r6/r13): QK^T (log2 domain) -> masked exp2 -> Psm -> PV.
// All indices static after inlining; Psm[w] reused serially per wave (DS
// ordering via lgkmcnt(0), no barrier). r20's pair-fused variant REGRESSED
// (+8us: doubled live sc/o/aq registers beat the LDS-read dedup).
__device__ __forceinline__ void attn_tile(int kb, int qmin, const short8 aq[2],
                                          const ushort_t* __restrict__ Ks,
                                          const ushort_t* __restrict__ Vs,
                                          ushort_t* __restrict__ Pw,
                                          f32x4 o[4], f32x4& lacc, short8 ones,
                                          int l16, int quad) {
    f32x4 sc[4];
    __builtin_amdgcn_s_setprio(1);
    #pragma unroll
    for (int nt = 0; nt < 4; ++nt) {
        int row = nt * 16 + l16;
        short8 bk0 = *(const short8*)&Ks[row * 64 + ((0 + quad) ^ (l16 & 7)) * 8];
        short8 bk1 = *(const short8*)&Ks[row * 64 + ((4 + quad) ^ (l16 & 7)) * 8];
        f32x4 cc = (f32x4){0.f, 0.f, 0.f, 0.f};
        cc = __builtin_amdgcn_mfma_f32_16x16x32_bf16(aq[0], bk0, cc, 0, 0, 0);
        cc = __builtin_amdgcn_mfma_f32_16x16x32_bf16(aq[1], bk1, cc, 0, 0, 0);
        sc[nt] = cc;
    }
    __builtin_amdgcn_s_setprio(0);

    bool msk = (kb + 63 > qmin);
    #pragma unroll
    for (int r = 0; r < 4; ++r) {
        float e0, e1, e2, e3;
        if (msk) {
            int qg = qmin + quad * 4 + r;
            e0 = (kb +  0 + l16 <= qg) ? __builtin_amdgcn_exp2f(sc[0][r]) : 0.f;
            e1 = (kb + 16 + l16 <= qg) ? __builtin_amdgcn_exp2f(sc[1][r]) : 0.f;
            e2 = (kb + 32 + l16 <= qg) ? __builtin_amdgcn_exp2f(sc[2][r]) : 0.f;
            e3 = (kb + 48 + l16 <= qg) ? __builtin_amdgcn_exp2f(sc[3][r]) : 0.f;
        } else {
            e0 = __builtin_amdgcn_exp2f(sc[0][r]);
            e1 = __builtin_amdgcn_exp2f(sc[1][r]);
            e2 = __builtin_amdgcn_exp2f(sc[2][r]);
            e3 = __builtin_amdgcn_exp2f(sc[3][r]);
        }
        uint2 pk = { pack_bf2(e0, e1), pack_bf2(e2, e3) };
        *(uint2*)&Pw[(quad * 4 + r) * 72 + l16 * 4] = pk;
    }

    asm volatile("s_waitcnt lgkmcnt(0)" ::: "memory");

    __builtin_amdgcn_s_setprio(1);
    #pragma unroll
    for (int kc = 0; kc < 2; ++kc) {
        short8 ap = *(const short8*)&Pw[l16 * 72 + kc * 32 + quad * 8];
        lacc = __builtin_amdgcn_mfma_f32_16x16x32_bf16(ap, ones, lacc, 0, 0, 0);
        #pragma unroll
        for (int dt = 0; dt < 4; ++dt) {
            int row = dt * 16 + l16;
            short8 bv = *(const short8*)&Vs[row * 64 + ((kc * 4 + quad) ^ (l16 & 7)) * 8];
            o[dt] = __builtin_amdgcn_mfma_f32_16x16x32_bf16(ap, bv, o[dt], 0, 0, 0);
        }
    }
    __builtin_amdgcn_s_setprio(0);
}

// ---------------- Flash attention: merged-phase single kt-sweep (r17 best) ---
// One kt-sweep serves both q-tiles (qt=p, qt=15-p) from the same staged K/V
// buffer — tiles 0..2p+1 no longer staged/barriered twice (r17: -4us vs
// two-phase). Sync skeleton: 1 barrier/tile, double-buffer, r13 activation
// predicate per tile (wave-uniform). r20's pair-fusion regressed; serial
// per-tile calls let the compiler retire one tile's registers before the
// next — keep them serial.
__global__ __launch_bounds__(512) void attn_kernel(const ushort_t* __restrict__ xq,
                                                   const ushort_t* __restrict__ xk,
                                                   const ushort_t* __restrict__ xvT,
                                                   ushort_t* __restrict__ ao) {
    __shared__ __align__(16) ushort_t Ksm[2][64 * 64];
    __shared__ __align__(16) ushort_t Vsm[2][64 * 64];
    __shared__ __align__(16) ushort_t Psm[8][16 * 72];

    int tid = threadIdx.x;
    int w = tid >> 6, lane = tid & 63;
    int l16 = lane & 15, quad = lane >> 4;
    int bh = blockIdx.x & 63;
    int p  = blockIdx.x >> 6;          // 0..7
    int b = bh >> 4, h = bh & 15;

    const ushort_t* Q  = xq  + (size_t)bh * SS * HD;
    const ushort_t* K  = xk  + (size_t)bh * SS * HD;
    const ushort_t* VT = xvT + (size_t)bh * HD * SS;

    int r0 = tid >> 3, j0 = ((tid & 7) ^ (r0 & 7)) * 8;
    int ldsb = (w * 64) * 8;

    short8 ones;
    #pragma unroll
    for (int i = 0; i < 8; ++i) ones[i] = (short)0x3F80;   // bf16 1.0

    const float CS = 0.125f * 1.44269504f;   // scale * log2(e), folded into Q

    int qmin_lo = p * 128 + w * 16;
    int qmin_hi = (15 - p) * 128 + w * 16;
    int ktmax   = 2 * (15 - p) + 1;    // last tile touching the hi q-tile

    // Q fragments for both tiles, pre-scaled by CS
    short8 aqlo[2], aqhi[2];
    #pragma unroll
    for (int kc = 0; kc < 2; ++kc) {
        short8 t0 = *(const short8*)(Q + (size_t)(qmin_lo + l16) * HD + kc * 32 + quad * 8);
        short8 t1 = *(const short8*)(Q + (size_t)(qmin_hi + l16) * HD + kc * 32 + quad * 8);
        #pragma unroll
        for (int i = 0; i < 8; ++i) {
            t0[i] = (short)f2bf(bf2f((ushort_t)t0[i]) * CS);
            t1[i] = (short)f2bf(bf2f((ushort_t)t1[i]) * CS);
        }
        aqlo[kc] = t0; aqhi[kc] = t1;
    }

    f32x4 olo[4], ohi[4];
    #pragma unroll
    for (int dt = 0; dt < 4; ++dt) {
        olo[dt] = (f32x4){0.f, 0.f, 0.f, 0.f};
        ohi[dt] = (f32x4){0.f, 0.f, 0.f, 0.f};
    }
    f32x4 lacclo = (f32x4){0.f, 0.f, 0.f, 0.f};
    f32x4 lacchi = (f32x4){0.f, 0.f, 0.f, 0.f};

    // prologue: stage tile 0 into buf0 (no prior readers of LDS)
    async16(K  + (size_t)r0 * HD + j0, &Ksm[0][ldsb]);
    async16(VT + (size_t)r0 * SS + j0, &Vsm[0][ldsb]);

    for (int kt = 0; kt <= ktmax; ++kt) {
        int kb = kt * 64;
        int c = kt & 1;
        __syncthreads();                    // stage(kt) published; kt-1 readers done
        if (kt < ktmax) {                   // prefetch kt+1 into other buffer
            int kb1 = kb + 64;
            async16(K  + (size_t)(kb1 + r0) * HD + j0, &Ksm[c ^ 1][ldsb]);
            async16(VT + (size_t)r0 * SS + kb1 + j0, &Vsm[c ^ 1][ldsb]);
        }

        if (kb <= qmin_lo + 15)             // lo tile active (wave-uniform)
            attn_tile(kb, qmin_lo, aqlo, &Ksm[c][0], &Vsm[c][0], &Psm[w][0],
                      olo, lacclo, ones, l16, quad);
        if (kb <= qmin_hi + 15)             // hi tile active (wave-uniform)
            attn_tile(kb, qmin_hi, aqhi, &Ksm[c][0], &Vsm[c][0], &Psm[w][0],
                      ohi, lacchi, ones, l16, quad);
    }

    // ---- epilogue: normalize by MFMA row sums, store bf16 (both tiles) ----
    #pragma unroll
    for (int r = 0; r < 4; ++r) {
        float invl = 1.0f / lacclo[r];
        float invh = 1.0f / lacchi[r];
        int qgl = qmin_lo + quad * 4 + r;
        int qgh = qmin_hi + quad * 4 + r;
        #pragma unroll
        for (int dt = 0; dt < 4; ++dt) {
            ao[((size_t)(b * SS + qgl)) * DD + h * HD + dt * 16 + l16] = f2bf(olo[dt][r] * invl);
            ao[((size_t)(b * SS + qgh)) * DD + h * HD + dt * 16 + l16] = f2bf(ohi[dt][r] * invh);
        }
    }
}

// ---------------------------------------------------------------------------
extern "C" void kernel_launch(void* const* d_in, const int* in_sizes, int n_in,
                              void* d_out, int out_size, void* d_ws, size_t ws_size,
                              hipStream_t stream) {
    const float* q  = (const float*)d_in[0];
    const float* k  = (const float*)d_in[1];
    const float* v  = (const float*)d_in[2];
    const float* wq = (const float*)d_in[3];
    const float* wk = (const float*)d_in[4];
    const float* wv = (const float*)d_in[5];
    const float* wo = (const float*)d_in[6];
    float* out = (float*)d_out;

    // ws (halves): wbf[4M] | xq[8M] | xk[8M] | xvT[8M] | vbf/ao[8M] = 72 MB.
    // qbf/kbf live in d_out (32 MB): dead scratch until out_gemm writes it.
    ushort_t* wbf = (ushort_t*)d_ws;
    ushort_t* xq  = wbf + 4194304ull;
    ushort_t* xk  = xq  + 8388608ull;
    ushort_t* xvT = xk  + 8388608ull;
    ushort_t* ao  = xvT + 8388608ull;
    ushort_t* vbf = ao;
    ushort_t* qbf = (ushort_t*)d_out;
    ushort_t* kbf = qbf + 8388608ull;

    cvt_all<<<14336, 256, 0, stream>>>(q, k, v, wq, wk, wv, wo, qbf, kbf, vbf, wbf);
    proj3f<<<1536, 512, 0, stream>>>(qbf, kbf, vbf, wbf, xq, xk, xvT);
    attn_kernel<<<512, 512, 0, stream>>>(xq, xk, xvT, ao);
    out_gemm<<<512, 512, 0, stream>>>(ao, wbf + 3145728ull, out);
}

// Round 23
// 306.633 us; speedup vs baseline: 1.0162x; 1.0162x over previous
//
#include <hip/hip_runtime.h>

#define SS 2048
#define DD 1024
#define HH 16
#define HD 64
#define MM 8192   // B*S

typedef unsigned short ushort_t;
typedef __attribute__((ext_vector_type(8))) short short8;
typedef __attribute__((ext_vector_type(4))) float f32x4;
typedef __attribute__((ext_vector_type(4))) unsigned short us4;
typedef __attribute__((ext_vector_type(8))) unsigned short us8;

__device__ __forceinline__ ushort_t f2bf(float f) {
    union { float f; unsigned u; } x; x.f = f;
    unsigned r = x.u + 0x7fffu + ((x.u >> 16) & 1u);
    return (ushort_t)(r >> 16);
}
__device__ __forceinline__ float bf2f(ushort_t h) {
    union { unsigned u; float f; } x; x.u = ((unsigned)h) << 16; return x.f;
}
// [hi16(b)<<16 | hi16(a)]: truncating bf16 pack of two fp32, one v_perm
__device__ __forceinline__ unsigned pack_bf2(float a, float b) {
    union { float f; unsigned u; } x, y; x.f = a; y.f = b;
    return __builtin_amdgcn_perm(y.u, x.u, 0x07060302u);
}

// async global->LDS, 16B per lane. LDS dst = wave-uniform base + lane*16.
__device__ __forceinline__ void async16(const void* g, void* l) {
    __builtin_amdgcn_global_load_lds(
        (const __attribute__((address_space(1))) unsigned int*)g,
        (__attribute__((address_space(3))) unsigned int*)l, 16, 0, 0);
}

// ---------------- cvt fp32 -> bf16: q,k,v (8M each) + 4 weights (1M each) ----
// Dedicated memory-bound pass (r0/r9 proved in-GEMM variants lose more).
// Flat 14336-block launch (r18's grid-stride regressed +9us).
// r22: attn's softmax scale CS = 0.125*log2(e) folded into wq here — xq is
// consumed ONLY by attn as Q, so pre-scaling removes attn's per-fragment
// unpack/mul/repack loop AND one bf16 rounding step.
__global__ void cvt_all(const float* __restrict__ q, const float* __restrict__ k,
                        const float* __restrict__ v, const float* __restrict__ wq,
                        const float* __restrict__ wk, const float* __restrict__ wv,
                        const float* __restrict__ wo, ushort_t* __restrict__ qbf,
                        ushort_t* __restrict__ kbf, ushort_t* __restrict__ vbf,
                        ushort_t* __restrict__ wbf) {
    long i = ((long)blockIdx.x * 256 + threadIdx.x) * 8;
    const float* src; ushort_t* dst;
    float sc = 1.0f;
    if (i < (3l << 23)) {
        int s = (int)(i >> 23);
        long off = i & ((1l << 23) - 1);
        src = ((s == 0) ? q : (s == 1) ? k : v) + off;
        dst = ((s == 0) ? qbf : (s == 1) ? kbf : vbf) + off;
    } else {
        long j = i - (3l << 23);
        int s = (int)(j >> 20);
        src = ((s == 0) ? wq : (s == 1) ? wk : (s == 2) ? wv : wo) + (j & 1048575);
        dst = wbf + j;
        if (s == 0) sc = 0.125f * 1.44269504f;   // CS folded into wq
    }
    float4 f0 = *(const float4*)src;
    float4 f1 = *(const float4*)(src + 4);
    us8 o;
    o[0] = f2bf(f0.x * sc); o[1] = f2bf(f0.y * sc); o[2] = f2bf(f0.z * sc); o[3] = f2bf(f0.w * sc);
    o[4] = f2bf(f1.x * sc); o[5] = f2bf(f1.y * sc); o[6] = f2bf(f1.z * sc); o[7] = f2bf(f1.w * sc);
    *(us8*)dst = o;
}

// ---------------- epilogue store --------------------------------------------
// mode 0: bf16 [B,H,S,HD]; mode 1: bf16 [B,H,HD,S] with key-permuted S;
// mode 2: fp32 row-major [M,D]
__device__ __forceinline__ void epi_store(int row, int col, float vf, int mode,
                                          void* Yv) {
    if (mode == 2) {
        ((float*)Yv)[(size_t)row * DD + col] = vf;
    } else {
        ushort_t vh = f2bf(vf);
        int b = row >> 11, s = row & 2047;
        int h = col >> 6,  hd = col & 63;
        if (mode == 0) {
            ((ushort_t*)Yv)[(((size_t)b * HH + h) * SS + s) * HD + hd] = vh;
        } else {
            // key k = s%64 stored at pos (k&15)*4 + (k>>4)&3
            int sp = (s & ~63) | (((s & 15) << 2) | ((s >> 4) & 3));
            ((ushort_t*)Yv)[(((size_t)b * HH + h) * HD + hd) * SS + sp] = vh;
        }
    }
}

// ---------------- shared GEMM body: 128^2, 8 waves, 3-buf T4 (session best) --
// r12/r14-verified: proj3f 89us, MfmaUtil 23.7, occ 51%. Per-wave 64x32
// (acc[4][2]), 3 LDS buffers, prefetch depth 2, vmcnt 4/2/0, 1 A + 1 B
// staging granule per thread, (r&3) granule XOR.
// CLOSED variants (all measured worse): 2-buf/32KB (r13: +8us); deepened XOR
// (r15: +8us); 256-row tile (r2); fp32-A staging (r9); 4-wave blocks (+12us).
__device__ __forceinline__ void gemm128_body(const ushort_t* __restrict__ A,
                                             const ushort_t* __restrict__ Bw,
                                             int m0, int n0, int mode, void* Y,
                                             ushort_t (*As)[128 * 32],
                                             ushort_t (*Bs)[128 * 32]) {
    int tid = threadIdx.x;
    int w = tid >> 6, lane = tid & 63;
    int l16 = lane & 15, quad = lane >> 4;
    int wm = (w >> 2) * 64, wn = (w & 3) * 32;   // 2M x 4N waves, 64x32 each

    f32x4 acc[4][2];
    #pragma unroll
    for (int i = 0; i < 4; ++i)
        #pragma unroll
        for (int j = 0; j < 2; ++j) acc[i][j] = (f32x4){0.f, 0.f, 0.f, 0.f};

    int r0 = tid >> 2, j0 = ((tid & 3) ^ (r0 & 3)) * 8;
    int swA = (quad ^ (l16 & 3)) * 8;

    const ushort_t* Ar0 = A  + (size_t)(m0 + r0) * DD + j0;
    const ushort_t* Br0 = Bw + (size_t)(n0 + r0) * DD + j0;
    int ldsb = w * 64 * 8;                        // wave-uniform base

    // prologue: stage k=0 -> buf0, k=1 -> buf1 (4 loads outstanding)
    async16(Ar0,      &As[0][ldsb]);
    async16(Br0,      &Bs[0][ldsb]);
    async16(Ar0 + 32, &As[1][ldsb]);
    async16(Br0 + 32, &Bs[1][ldsb]);

    int c = 0, c2 = 2;   // compute buffer, stage-target buffer (= c+2 mod 3)
    for (int kk = 0; kk < 32; ++kk) {
        __builtin_amdgcn_s_barrier();          // iter kk-1 readers of buf c2 done
        if (kk < 30) {
            int k2 = (kk + 2) * 32;
            async16(Ar0 + k2, &As[c2][ldsb]);
            async16(Br0 + k2, &Bs[c2][ldsb]);
            asm volatile("s_waitcnt vmcnt(4)" ::: "memory");   // stage(kk) landed
        } else if (kk == 30) {
            asm volatile("s_waitcnt vmcnt(2)" ::: "memory");
        } else {
            asm volatile("s_waitcnt vmcnt(0)" ::: "memory");
        }
        __builtin_amdgcn_s_barrier();          // ALL waves' stage(kk) landed
        __builtin_amdgcn_sched_barrier(0);

        short8 af[4], bfr[2];
        #pragma unroll
        for (int t = 0; t < 4; ++t)
            af[t] = *(const short8*)&As[c][(wm + t * 16 + l16) * 32 + swA];
        #pragma unroll
        for (int t = 0; t < 2; ++t)
            bfr[t] = *(const short8*)&Bs[c][(wn + t * 16 + l16) * 32 + swA];
        #pragma unroll
        for (int mt = 0; mt < 4; ++mt)
            #pragma unroll
            for (int nt = 0; nt < 2; ++nt)
                acc[mt][nt] = __builtin_amdgcn_mfma_f32_16x16x32_bf16(af[mt], bfr[nt], acc[mt][nt], 0, 0, 0);

        c  = (c  == 2) ? 0 : c  + 1;
        c2 = (c2 == 2) ? 0 : c2 + 1;
    }

    #pragma unroll
    for (int mt = 0; mt < 4; ++mt)
        #pragma unroll
        for (int r = 0; r < 4; ++r) {
            int row = m0 + wm + mt * 16 + quad * 4 + r;
            #pragma unroll
            for (int nt = 0; nt < 2; ++nt)
                epi_store(row, n0 + wn + nt * 16 + l16, acc[mt][nt][r], mode, Y);
        }
}

// ---------------- fused projections ------------------------------------------
__global__ __launch_bounds__(512) void proj3f(const ushort_t* __restrict__ qbf,
                                              const ushort_t* __restrict__ kbf,
                                              const ushort_t* __restrict__ vbf,
                                              const ushort_t* __restrict__ Wall,
                                              ushort_t* __restrict__ xq,
                                              ushort_t* __restrict__ xk,
                                              ushort_t* __restrict__ xvT) {
    __shared__ __align__(16) ushort_t As[3][128 * 32];
    __shared__ __align__(16) ushort_t Bs[3][128 * 32];
    int mat   = (int)(blockIdx.x >> 9);
    int inner = (int)(blockIdx.x & 511);
    int m0 = (inner & 63) * 128;     // XCD swizzle: A-panel sharers on one XCD
    int n0 = (inner >> 6) * 128;
    const ushort_t* A  = (mat == 0) ? qbf : (mat == 1) ? kbf : vbf;
    const ushort_t* Bw = Wall + ((size_t)mat << 20);
    void* Y = (mat == 0) ? (void*)xq : (mat == 1) ? (void*)xk : (void*)xvT;
    gemm128_body(A, Bw, m0, n0, (mat == 2) ? 1 : 0, Y, As, Bs);
}

// ---------------- output GEMM ------------------------------------------------
__global__ __launch_bounds__(512) void out_gemm(const ushort_t* __restrict__ Abf,
                                                const ushort_t* __restrict__ Bw,
                                                float* __restrict__ Y) {
    __shared__ __align__(16) ushort_t As[3][128 * 32];
    __shared__ __align__(16) ushort_t Bs[3][128 * 32];
    int m0 = (int)(blockIdx.x & 63) * 128;   // XCD swizzle
    int n0 = (int)(blockIdx.x >> 6) * 128;
    gemm128_body(Abf, Bw, m0, n0, 2, (void*)Y, As, Bs);
}

// ---------------- attn per-tile compute body ---------------------------------
// Verified body (r6/r13): QK^T (log2 domain; Q pre-scaled via wq) -> masked
// exp2 -> Psm -> PV. Psm[w] reused serially per wave (lgkmcnt(0), no
// barrier). r20's pair-fused variant REGRESSED (+8us register pressure).
__device__ __forceinline__ void attn_tile(int kb, int qmin, const short8 aq[2],
                                          const ushort_t* __restrict__ Ks,
                                          const ushort_t* __restrict__ Vs,
                                          ushort_t* __restrict__ Pw,
                                          f32x4 o[4], f32x4& lacc, short8 ones,
                                          int l16, int quad) {
    f32x4 sc[4];
    __builtin_amdgcn_s_setprio(1);
    #pragma unroll
    for (int nt = 0; nt < 4; ++nt) {
        int row = nt * 16 + l16;
        short8 bk0 = *(const short8*)&Ks[row * 64 + ((0 + quad) ^ (l16 & 7)) * 8];
        short8 bk1 = *(const short8*)&Ks[row * 64 + ((4 + quad) ^ (l16 & 7)) * 8];
        f32x4 cc = (f32x4){0.f, 0.f, 0.f, 0.f};
        cc = __builtin_amdgcn_mfma_f32_16x16x32_bf16(aq[0], bk0, cc, 0, 0, 0);
        cc = __builtin_amdgcn_mfma_f32_16x16x32_bf16(aq[1], bk1, cc, 0, 0, 0);
        sc[nt] = cc;
    }
    __builtin_amdgcn_s_setprio(0);

    bool msk = (kb + 63 > qmin);
    #pragma unroll
    for (int r = 0; r < 4; ++r) {
        float e0, e1, e2, e3;
        if (msk) {
            int qg = qmin + quad * 4 + r;
            e0 = (kb +  0 + l16 <= qg) ? __builtin_amdgcn_exp2f(sc[0][r]) : 0.f;
            e1 = (kb + 16 + l16 <= qg) ? __builtin_amdgcn_exp2f(sc[1][r]) : 0.f;
            e2 = (kb + 32 + l16 <= qg) ? __builtin_amdgcn_exp2f(sc[2][r]) : 0.f;
            e3 = (kb + 48 + l16 <= qg) ? __builtin_amdgcn_exp2f(sc[3][r]) : 0.f;
        } else {
            e0 = __builtin_amdgcn_exp2f(sc[0][r]);
            e1 = __builtin_amdgcn_exp2f(sc[1][r]);
            e2 = __builtin_amdgcn_exp2f(sc[2][r]);
            e3 = __builtin_amdgcn_exp2f(sc[3][r]);
        }
        uint2 pk = { pack_bf2(e0, e1), pack_bf2(e2, e3) };
        *(uint2*)&Pw[(quad * 4 + r) * 72 + l16 * 4] = pk;
    }

    asm volatile("s_waitcnt lgkmcnt(0)" ::: "memory");

    __builtin_amdgcn_s_setprio(1);
    #pragma unroll
    for (int kc = 0; kc < 2; ++kc) {
        short8 ap = *(const short8*)&Pw[l16 * 72 + kc * 32 + quad * 8];
        lacc = __builtin_amdgcn_mfma_f32_16x16x32_bf16(ap, ones, lacc, 0, 0, 0);
        #pragma unroll
        for (int dt = 0; dt < 4; ++dt) {
            int row = dt * 16 + l16;
            short8 bv = *(const short8*)&Vs[row * 64 + ((kc * 4 + quad) ^ (l16 & 7)) * 8];
            o[dt] = __builtin_amdgcn_mfma_f32_16x16x32_bf16(ap, bv, o[dt], 0, 0, 0);
        }
    }
    __builtin_amdgcn_s_setprio(0);
}

// ---------------- Flash attention: merged-phase single kt-sweep (r17 best) ---
// One kt-sweep serves both q-tiles (qt=p, qt=15-p) from the same staged K/V
// buffer (r17: -4us vs two-phase). 1 barrier/tile, double-buffer, r13
// activation predicate per tile (wave-uniform). Q arrives pre-scaled by CS
// (folded into wq at cvt) — plain vector load, no repack loop.
__global__ __launch_bounds__(512) void attn_kernel(const ushort_t* __restrict__ xq,
                                                   const ushort_t* __restrict__ xk,
                                                   const ushort_t* __restrict__ xvT,
                                                   ushort_t* __restrict__ ao) {
    __shared__ __align__(16) ushort_t Ksm[2][64 * 64];
    __shared__ __align__(16) ushort_t Vsm[2][64 * 64];
    __shared__ __align__(16) ushort_t Psm[8][16 * 72];

    int tid = threadIdx.x;
    int w = tid >> 6, lane = tid & 63;
    int l16 = lane & 15, quad = lane >> 4;
    int bh = blockIdx.x & 63;
    int p  = blockIdx.x >> 6;          // 0..7
    int b = bh >> 4, h = bh & 15;

    const ushort_t* Q  = xq  + (size_t)bh * SS * HD;
    const ushort_t* K  = xk  + (size_t)bh * SS * HD;
    const ushort_t* VT = xvT + (size_t)bh * HD * SS;

    int r0 = tid >> 3, j0 = ((tid & 7) ^ (r0 & 7)) * 8;
    int ldsb = (w * 64) * 8;

    short8 ones;
    #pragma unroll
    for (int i = 0; i < 8; ++i) ones[i] = (short)0x3F80;   // bf16 1.0

    int qmin_lo = p * 128 + w * 16;
    int qmin_hi = (15 - p) * 128 + w * 16;
    int ktmax   = 2 * (15 - p) + 1;    // last tile touching the hi q-tile

    // Q fragments for both tiles (pre-scaled at cvt; plain loads)
    short8 aqlo[2], aqhi[2];
    #pragma unroll
    for (int kc = 0; kc < 2; ++kc) {
        aqlo[kc] = *(const short8*)(Q + (size_t)(qmin_lo + l16) * HD + kc * 32 + quad * 8);
        aqhi[kc] = *(const short8*)(Q + (size_t)(qmin_hi + l16) * HD + kc * 32 + quad * 8);
    }

    f32x4 olo[4], ohi[4];
    #pragma unroll
    for (int dt = 0; dt < 4; ++dt) {
        olo[dt] = (f32x4){0.f, 0.f, 0.f, 0.f};
        ohi[dt] = (f32x4){0.f, 0.f, 0.f, 0.f};
    }
    f32x4 lacclo = (f32x4){0.f, 0.f, 0.f, 0.f};
    f32x4 lacchi = (f32x4){0.f, 0.f, 0.f, 0.f};

    // prologue: stage tile 0 into buf0 (no prior readers of LDS)
    async16(K  + (size_t)r0 * HD + j0, &Ksm[0][ldsb]);
    async16(VT + (size_t)r0 * SS + j0, &Vsm[0][ldsb]);

    for (int kt = 0; kt <= ktmax; ++kt) {
        int kb = kt * 64;
        int c = kt & 1;
        __syncthreads();                    // stage(kt) published; kt-1 readers done
        if (kt < ktmax) {                   // prefetch kt+1 into other buffer
            int kb1 = kb + 64;
            async16(K  + (size_t)(kb1 + r0) * HD + j0, &Ksm[c ^ 1][ldsb]);
            async16(VT + (size_t)r0 * SS + kb1 + j0, &Vsm[c ^ 1][ldsb]);
        }

        if (kb <= qmin_lo + 15)             // lo tile active (wave-uniform)
            attn_tile(kb, qmin_lo, aqlo, &Ksm[c][0], &Vsm[c][0], &Psm[w][0],
                      olo, lacclo, ones, l16, quad);
        if (kb <= qmin_hi + 15)             // hi tile active (wave-uniform)
            attn_tile(kb, qmin_hi, aqhi, &Ksm[c][0], &Vsm[c][0], &Psm[w][0],
                      ohi, lacchi, ones, l16, quad);
    }

    // ---- epilogue: normalize by MFMA row sums, store bf16 (both tiles) ----
    #pragma unroll
    for (int r = 0; r < 4; ++r) {
        float invl = 1.0f / lacclo[r];
        float invh = 1.0f / lacchi[r];
        int qgl = qmin_lo + quad * 4 + r;
        int qgh = qmin_hi + quad * 4 + r;
        #pragma unroll
        for (int dt = 0; dt < 4; ++dt) {
            ao[((size_t)(b * SS + qgl)) * DD + h * HD + dt * 16 + l16] = f2bf(olo[dt][r] * invl);
            ao[((size_t)(b * SS + qgh)) * DD + h * HD + dt * 16 + l16] = f2bf(ohi[dt][r] * invh);
        }
    }
}

// ---------------------------------------------------------------------------
extern "C" void kernel_launch(void* const* d_in, const int* in_sizes, int n_in,
                              void* d_out, int out_size, void* d_ws, size_t ws_size,
                              hipStream_t stream) {
    const float* q  = (const float*)d_in[0];
    const float* k  = (const float*)d_in[1];
    const float* v  = (const float*)d_in[2];
    const float* wq = (const float*)d_in[3];
    const float* wk = (const float*)d_in[4];
    const float* wv = (const float*)d_in[5];
    const float* wo = (const float*)d_in[6];
    float* out = (float*)d_out;

    // ws (halves): wbf[4M] | xq[8M] | xk[8M] | xvT[8M] | vbf/ao[8M] = 72 MB.
    // qbf/kbf live in d_out (32 MB): dead scratch until out_gemm writes it.
    ushort_t* wbf = (ushort_t*)d_ws;
    ushort_t* xq  = wbf + 4194304ull;
    ushort_t* xk  = xq  + 8388608ull;
    ushort_t* xvT = xk  + 8388608ull;
    ushort_t* ao  = xvT + 8388608ull;
    ushort_t* vbf = ao;
    ushort_t* qbf = (ushort_t*)d_out;
    ushort_t* kbf = qbf + 8388608ull;

    cvt_all<<<14336, 256, 0, stream>>>(q, k, v, wq, wk, wv, wo, qbf, kbf, vbf, wbf);
    proj3f<<<1536, 512, 0, stream>>>(qbf, kbf, vbf, wbf, xq, xk, xvT);
    attn_kernel<<<512, 512, 0, stream>>>(xq, xk, xvT, ao);
    out_gemm<<<512, 512, 0, stream>>>(ao, wbf + 3145728ull, out);
}

// Round 24
// 300.227 us; speedup vs baseline: 1.0379x; 1.0213x over previous
//
#include <hip/hip_runtime.h>

#define SS 2048
#define DD 1024
#define HH 16
#define HD 64
#define MM 8192   // B*S

typedef unsigned short ushort_t;
typedef __attribute__((ext_vector_type(8))) short short8;
typedef __attribute__((ext_vector_type(4))) float f32x4;
typedef __attribute__((ext_vector_type(4))) unsigned short us4;
typedef __attribute__((ext_vector_type(8))) unsigned short us8;

__device__ __forceinline__ ushort_t f2bf(float f) {
    union { float f; unsigned u; } x; x.f = f;
    unsigned r = x.u + 0x7fffu + ((x.u >> 16) & 1u);
    return (ushort_t)(r >> 16);
}
__device__ __forceinline__ float bf2f(ushort_t h) {
    union { unsigned u; float f; } x; x.u = ((unsigned)h) << 16; return x.f;
}
// [hi16(b)<<16 | hi16(a)]: truncating bf16 pack of two fp32, one v_perm
__device__ __forceinline__ unsigned pack_bf2(float a, float b) {
    union { float f; unsigned u; } x, y; x.f = a; y.f = b;
    return __builtin_amdgcn_perm(y.u, x.u, 0x07060302u);
}

// async global->LDS, 16B per lane. LDS dst = wave-uniform base + lane*16.
__device__ __forceinline__ void async16(const void* g, void* l) {
    __builtin_amdgcn_global_load_lds(
        (const __attribute__((address_space(1))) unsigned int*)g,
        (__attribute__((address_space(3))) unsigned int*)l, 16, 0, 0);
}

// ---------------- cvt fp32 -> bf16: q,k,v (8M each) + 4 weights (1M each) ----
// Dedicated memory-bound pass (r0/r9 proved in-GEMM variants lose more).
// Flat 14336-block launch (r18's grid-stride regressed +9us).
// r22: attn's softmax scale CS = 0.125*log2(e) folded into wq here — xq is
// consumed ONLY by attn as Q, so pre-scaling removes attn's per-fragment
// unpack/mul/repack loop AND one bf16 rounding step.
__global__ void cvt_all(const float* __restrict__ q, const float* __restrict__ k,
                        const float* __restrict__ v, const float* __restrict__ wq,
                        const float* __restrict__ wk, const float* __restrict__ wv,
                        const float* __restrict__ wo, ushort_t* __restrict__ qbf,
                        ushort_t* __restrict__ kbf, ushort_t* __restrict__ vbf,
                        ushort_t* __restrict__ wbf) {
    long i = ((long)blockIdx.x * 256 + threadIdx.x) * 8;
    const float* src; ushort_t* dst;
    float sc = 1.0f;
    if (i < (3l << 23)) {
        int s = (int)(i >> 23);
        long off = i & ((1l << 23) - 1);
        src = ((s == 0) ? q : (s == 1) ? k : v) + off;
        dst = ((s == 0) ? qbf : (s == 1) ? kbf : vbf) + off;
    } else {
        long j = i - (3l << 23);
        int s = (int)(j >> 20);
        src = ((s == 0) ? wq : (s == 1) ? wk : (s == 2) ? wv : wo) + (j & 1048575);
        dst = wbf + j;
        if (s == 0) sc = 0.125f * 1.44269504f;   // CS folded into wq
    }
    float4 f0 = *(const float4*)src;
    float4 f1 = *(const float4*)(src + 4);
    us8 o;
    o[0] = f2bf(f0.x * sc); o[1] = f2bf(f0.y * sc); o[2] = f2bf(f0.z * sc); o[3] = f2bf(f0.w * sc);
    o[4] = f2bf(f1.x * sc); o[5] = f2bf(f1.y * sc); o[6] = f2bf(f1.z * sc); o[7] = f2bf(f1.w * sc);
    *(us8*)dst = o;
}

// ---------------- epilogue store --------------------------------------------
// mode 0: bf16 [B,H,S,HD]; mode 1: bf16 [B,H,HD,S] with key-permuted S;
// mode 2: fp32 row-major [M,D]
__device__ __forceinline__ void epi_store(int row, int col, float vf, int mode,
                                          void* Yv) {
    if (mode == 2) {
        ((float*)Yv)[(size_t)row * DD + col] = vf;
    } else {
        ushort_t vh = f2bf(vf);
        int b = row >> 11, s = row & 2047;
        int h = col >> 6,  hd = col & 63;
        if (mode == 0) {
            ((ushort_t*)Yv)[(((size_t)b * HH + h) * SS + s) * HD + hd] = vh;
        } else {
            // key k = s%64 stored at pos (k&15)*4 + (k>>4)&3
            int sp = (s & ~63) | (((s & 15) << 2) | ((s >> 4) & 3));
            ((ushort_t*)Yv)[(((size_t)b * HH + h) * HD + hd) * SS + sp] = vh;
        }
    }
}

// ---------------- shared GEMM body: 128^2, 8 waves, 3-buf T4 (session best) --
// r12/r14-verified: proj3f 89us, MfmaUtil 23.7, occ 51%. Per-wave 64x32
// (acc[4][2]), 3 LDS buffers, prefetch depth 2, vmcnt 4/2/0, 1 A + 1 B
// staging granule per thread, (r&3) granule XOR.
// CLOSED variants (all measured worse): 2-buf/32KB (r13: +8us); deepened XOR
// (r15: +8us); 256-row tile (r2); fp32-A staging (r9); 4-wave blocks (+12us).
__device__ __forceinline__ void gemm128_body(const ushort_t* __restrict__ A,
                                             const ushort_t* __restrict__ Bw,
                                             int m0, int n0, int mode, void* Y,
                                             ushort_t (*As)[128 * 32],
                                             ushort_t (*Bs)[128 * 32]) {
    int tid = threadIdx.x;
    int w = tid >> 6, lane = tid & 63;
    int l16 = lane & 15, quad = lane >> 4;
    int wm = (w >> 2) * 64, wn = (w & 3) * 32;   // 2M x 4N waves, 64x32 each

    f32x4 acc[4][2];
    #pragma unroll
    for (int i = 0; i < 4; ++i)
        #pragma unroll
        for (int j = 0; j < 2; ++j) acc[i][j] = (f32x4){0.f, 0.f, 0.f, 0.f};

    int r0 = tid >> 2, j0 = ((tid & 3) ^ (r0 & 3)) * 8;
    int swA = (quad ^ (l16 & 3)) * 8;

    const ushort_t* Ar0 = A  + (size_t)(m0 + r0) * DD + j0;
    const ushort_t* Br0 = Bw + (size_t)(n0 + r0) * DD + j0;
    int ldsb = w * 64 * 8;                        // wave-uniform base

    // prologue: stage k=0 -> buf0, k=1 -> buf1 (4 loads outstanding)
    async16(Ar0,      &As[0][ldsb]);
    async16(Br0,      &Bs[0][ldsb]);
    async16(Ar0 + 32, &As[1][ldsb]);
    async16(Br0 + 32, &Bs[1][ldsb]);

    int c = 0, c2 = 2;   // compute buffer, stage-target buffer (= c+2 mod 3)
    for (int kk = 0; kk < 32; ++kk) {
        __builtin_amdgcn_s_barrier();          // iter kk-1 readers of buf c2 done
        if (kk < 30) {
            int k2 = (kk + 2) * 32;
            async16(Ar0 + k2, &As[c2][ldsb]);
            async16(Br0 + k2, &Bs[c2][ldsb]);
            asm volatile("s_waitcnt vmcnt(4)" ::: "memory");   // stage(kk) landed
        } else if (kk == 30) {
            asm volatile("s_waitcnt vmcnt(2)" ::: "memory");
        } else {
            asm volatile("s_waitcnt vmcnt(0)" ::: "memory");
        }
        __builtin_amdgcn_s_barrier();          // ALL waves' stage(kk) landed
        __builtin_amdgcn_sched_barrier(0);

        short8 af[4], bfr[2];
        #pragma unroll
        for (int t = 0; t < 4; ++t)
            af[t] = *(const short8*)&As[c][(wm + t * 16 + l16) * 32 + swA];
        #pragma unroll
        for (int t = 0; t < 2; ++t)
            bfr[t] = *(const short8*)&Bs[c][(wn + t * 16 + l16) * 32 + swA];
        #pragma unroll
        for (int mt = 0; mt < 4; ++mt)
            #pragma unroll
            for (int nt = 0; nt < 2; ++nt)
                acc[mt][nt] = __builtin_amdgcn_mfma_f32_16x16x32_bf16(af[mt], bfr[nt], acc[mt][nt], 0, 0, 0);

        c  = (c  == 2) ? 0 : c  + 1;
        c2 = (c2 == 2) ? 0 : c2 + 1;
    }

    #pragma unroll
    for (int mt = 0; mt < 4; ++mt)
        #pragma unroll
        for (int r = 0; r < 4; ++r) {
            int row = m0 + wm + mt * 16 + quad * 4 + r;
            #pragma unroll
            for (int nt = 0; nt < 2; ++nt)
                epi_store(row, n0 + wn + nt * 16 + l16, acc[mt][nt][r], mode, Y);
        }
}

// ---------------- fused projections ------------------------------------------
__global__ __launch_bounds__(512) void proj3f(const ushort_t* __restrict__ qbf,
                                              const ushort_t* __restrict__ kbf,
                                              const ushort_t* __restrict__ vbf,
                                              const ushort_t* __restrict__ Wall,
                                              ushort_t* __restrict__ xq,
                                              ushort_t* __restrict__ xk,
                                              ushort_t* __restrict__ xvT) {
    __shared__ __align__(16) ushort_t As[3][128 * 32];
    __shared__ __align__(16) ushort_t Bs[3][128 * 32];
    int mat   = (int)(blockIdx.x >> 9);
    int inner = (int)(blockIdx.x & 511);
    int m0 = (inner & 63) * 128;     // XCD swizzle: A-panel sharers on one XCD
    int n0 = (inner >> 6) * 128;
    const ushort_t* A  = (mat == 0) ? qbf : (mat == 1) ? kbf : vbf;
    const ushort_t* Bw = Wall + ((size_t)mat << 20);
    void* Y = (mat == 0) ? (void*)xq : (mat == 1) ? (void*)xk : (void*)xvT;
    gemm128_body(A, Bw, m0, n0, (mat == 2) ? 1 : 0, Y, As, Bs);
}

// ---------------- output GEMM ------------------------------------------------
__global__ __launch_bounds__(512) void out_gemm(const ushort_t* __restrict__ Abf,
                                                const ushort_t* __restrict__ Bw,
                                                float* __restrict__ Y) {
    __shared__ __align__(16) ushort_t As[3][128 * 32];
    __shared__ __align__(16) ushort_t Bs[3][128 * 32];
    int m0 = (int)(blockIdx.x & 63) * 128;   // XCD swizzle
    int n0 = (int)(blockIdx.x >> 6) * 128;
    gemm128_body(Abf, Bw, m0, n0, 2, (void*)Y, As, Bs);
}

// ---------------- attn per-tile compute body ---------------------------------
// Verified body (r6/r13): QK^T (log2 domain; Q pre-scaled via wq) -> masked
// exp2 -> Psm -> PV. Psm[w] reused serially per wave (lgkmcnt(0), no
// barrier). r20's pair-fused variant REGRESSED (+8us register pressure).
__device__ __forceinline__ void attn_tile(int kb, int qmin, const short8 aq[2],
                                          const ushort_t* __restrict__ Ks,
                                          const ushort_t* __restrict__ Vs,
                                          ushort_t* __restrict__ Pw,
                                          f32x4 o[4], f32x4& lacc, short8 ones,
                                          int l16, int quad) {
    f32x4 sc[4];
    __builtin_amdgcn_s_setprio(1);
    #pragma unroll
    for (int nt = 0; nt < 4; ++nt) {
        int row = nt * 16 + l16;
        short8 bk0 = *(const short8*)&Ks[row * 64 + ((0 + quad) ^ (l16 & 7)) * 8];
        short8 bk1 = *(const short8*)&Ks[row * 64 + ((4 + quad) ^ (l16 & 7)) * 8];
        f32x4 cc = (f32x4){0.f, 0.f, 0.f, 0.f};
        cc = __builtin_amdgcn_mfma_f32_16x16x32_bf16(aq[0], bk0, cc, 0, 0, 0);
        cc = __builtin_amdgcn_mfma_f32_16x16x32_bf16(aq[1], bk1, cc, 0, 0, 0);
        sc[nt] = cc;
    }
    __builtin_amdgcn_s_setprio(0);

    bool msk = (kb + 63 > qmin);
    #pragma unroll
    for (int r = 0; r < 4; ++r) {
        float e0, e1, e2, e3;
        if (msk) {
            int qg = qmin + quad * 4 + r;
            e0 = (kb +  0 + l16 <= qg) ? __builtin_amdgcn_exp2f(sc[0][r]) : 0.f;
            e1 = (kb + 16 + l16 <= qg) ? __builtin_amdgcn_exp2f(sc[1][r]) : 0.f;
            e2 = (kb + 32 + l16 <= qg) ? __builtin_amdgcn_exp2f(sc[2][r]) : 0.f;
            e3 = (kb + 48 + l16 <= qg) ? __builtin_amdgcn_exp2f(sc[3][r]) : 0.f;
        } else {
            e0 = __builtin_amdgcn_exp2f(sc[0][r]);
            e1 = __builtin_amdgcn_exp2f(sc[1][r]);
            e2 = __builtin_amdgcn_exp2f(sc[2][r]);
            e3 = __builtin_amdgcn_exp2f(sc[3][r]);
        }
        uint2 pk = { pack_bf2(e0, e1), pack_bf2(e2, e3) };
        *(uint2*)&Pw[(quad * 4 + r) * 72 + l16 * 4] = pk;
    }

    asm volatile("s_waitcnt lgkmcnt(0)" ::: "memory");

    __builtin_amdgcn_s_setprio(1);
    #pragma unroll
    for (int kc = 0; kc < 2; ++kc) {
        short8 ap = *(const short8*)&Pw[l16 * 72 + kc * 32 + quad * 8];
        lacc = __builtin_amdgcn_mfma_f32_16x16x32_bf16(ap, ones, lacc, 0, 0, 0);
        #pragma unroll
        for (int dt = 0; dt < 4; ++dt) {
            int row = dt * 16 + l16;
            short8 bv = *(const short8*)&Vs[row * 64 + ((kc * 4 + quad) ^ (l16 & 7)) * 8];
            o[dt] = __builtin_amdgcn_mfma_f32_16x16x32_bf16(ap, bv, o[dt], 0, 0, 0);
        }
    }
    __builtin_amdgcn_s_setprio(0);
}

// ---------------- Flash attention: merged-phase single kt-sweep (r17 best) ---
// One kt-sweep serves both q-tiles (qt=p, qt=15-p) from the same staged K/V
// buffer (r17: -4us vs two-phase). 1 barrier/tile, double-buffer, r13
// activation predicate per tile (wave-uniform). Q arrives pre-scaled by CS
// (folded into wq at cvt) — plain vector load, no repack loop.
__global__ __launch_bounds__(512) void attn_kernel(const ushort_t* __restrict__ xq,
                                                   const ushort_t* __restrict__ xk,
                                                   const ushort_t* __restrict__ xvT,
                                                   ushort_t* __restrict__ ao) {
    __shared__ __align__(16) ushort_t Ksm[2][64 * 64];
    __shared__ __align__(16) ushort_t Vsm[2][64 * 64];
    __shared__ __align__(16) ushort_t Psm[8][16 * 72];

    int tid = threadIdx.x;
    int w = tid >> 6, lane = tid & 63;
    int l16 = lane & 15, quad = lane >> 4;
    int bh = blockIdx.x & 63;
    int p  = blockIdx.x >> 6;          // 0..7
    int b = bh >> 4, h = bh & 15;

    const ushort_t* Q  = xq  + (size_t)bh * SS * HD;
    const ushort_t* K  = xk  + (size_t)bh * SS * HD;
    const ushort_t* VT = xvT + (size_t)bh * HD * SS;

    int r0 = tid >> 3, j0 = ((tid & 7) ^ (r0 & 7)) * 8;
    int ldsb = (w * 64) * 8;

    short8 ones;
    #pragma unroll
    for (int i = 0; i < 8; ++i) ones[i] = (short)0x3F80;   // bf16 1.0

    int qmin_lo = p * 128 + w * 16;
    int qmin_hi = (15 - p) * 128 + w * 16;
    int ktmax   = 2 * (15 - p) + 1;    // last tile touching the hi q-tile

    // Q fragments for both tiles (pre-scaled at cvt; plain loads)
    short8 aqlo[2], aqhi[2];
    #pragma unroll
    for (int kc = 0; kc < 2; ++kc) {
        aqlo[kc] = *(const short8*)(Q + (size_t)(qmin_lo + l16) * HD + kc * 32 + quad * 8);
        aqhi[kc] = *(const short8*)(Q + (size_t)(qmin_hi + l16) * HD + kc * 32 + quad * 8);
    }

    f32x4 olo[4], ohi[4];
    #pragma unroll
    for (int dt = 0; dt < 4; ++dt) {
        olo[dt] = (f32x4){0.f, 0.f, 0.f, 0.f};
        ohi[dt] = (f32x4){0.f, 0.f, 0.f, 0.f};
    }
    f32x4 lacclo = (f32x4){0.f, 0.f, 0.f, 0.f};
    f32x4 lacchi = (f32x4){0.f, 0.f, 0.f, 0.f};

    // prologue: stage tile 0 into buf0 (no prior readers of LDS)
    async16(K  + (size_t)r0 * HD + j0, &Ksm[0][ldsb]);
    async16(VT + (size_t)r0 * SS + j0, &Vsm[0][ldsb]);

    for (int kt = 0; kt <= ktmax; ++kt) {
        int kb = kt * 64;
        int c = kt & 1;
        __syncthreads();                    // stage(kt) published; kt-1 readers done
        if (kt < ktmax) {                   // prefetch kt+1 into other buffer
            int kb1 = kb + 64;
            async16(K  + (size_t)(kb1 + r0) * HD + j0, &Ksm[c ^ 1][ldsb]);
            async16(VT + (size_t)r0 * SS + kb1 + j0, &Vsm[c ^ 1][ldsb]);
        }

        if (kb <= qmin_lo + 15)             // lo tile active (wave-uniform)
            attn_tile(kb, qmin_lo, aqlo, &Ksm[c][0], &Vsm[c][0], &Psm[w][0],
                      olo, lacclo, ones, l16, quad);
        if (kb <= qmin_hi + 15)             // hi tile active (wave-uniform)
            attn_tile(kb, qmin_hi, aqhi, &Ksm[c][0], &Vsm[c][0], &Psm[w][0],
                      ohi, lacchi, ones, l16, quad);
    }

    // ---- epilogue: normalize by MFMA row sums, store bf16 (both tiles) ----
    #pragma unroll
    for (int r = 0; r < 4; ++r) {
        float invl = 1.0f / lacclo[r];
        float invh = 1.0f / lacchi[r];
        int qgl = qmin_lo + quad * 4 + r;
        int qgh = qmin_hi + quad * 4 + r;
        #pragma unroll
        for (int dt = 0; dt < 4; ++dt) {
            ao[((size_t)(b * SS + qgl)) * DD + h * HD + dt * 16 + l16] = f2bf(olo[dt][r] * invl);
            ao[((size_t)(b * SS + qgh)) * DD + h * HD + dt * 16 + l16] = f2bf(ohi[dt][r] * invh);
        }
    }
}

// ---------------------------------------------------------------------------
extern "C" void kernel_launch(void* const* d_in, const int* in_sizes, int n_in,
                              void* d_out, int out_size, void* d_ws, size_t ws_size,
                              hipStream_t stream) {
    const float* q  = (const float*)d_in[0];
    const float* k  = (const float*)d_in[1];
    const float* v  = (const float*)d_in[2];
    const float* wq = (const float*)d_in[3];
    const float* wk = (const float*)d_in[4];
    const float* wv = (const float*)d_in[5];
    const float* wo = (const float*)d_in[6];
    float* out = (float*)d_out;

    // ws (halves): wbf[4M] | xq[8M] | xk[8M] | xvT[8M] | vbf/ao[8M] = 72 MB.
    // qbf/kbf live in d_out (32 MB): dead scratch until out_gemm writes it.
    ushort_t* wbf = (ushort_t*)d_ws;
    ushort_t* xq  = wbf + 4194304ull;
    ushort_t* xk  = xq  + 8388608ull;
    ushort_t* xvT = xk  + 8388608ull;
    ushort_t* ao  = xvT + 8388608ull;
    ushort_t* vbf = ao;
    ushort_t* qbf = (ushort_t*)d_out;
    ushort_t* kbf = qbf + 8388608ull;

    cvt_all<<<14336, 256, 0, stream>>>(q, k, v, wq, wk, wv, wo, qbf, kbf, vbf, wbf);
    proj3f<<<1536, 512, 0, stream>>>(qbf, kbf, vbf, wbf, xq, xk, xvT);
    attn_kernel<<<512, 512, 0, stream>>>(xq, xk, xvT, ao);
    out_gemm<<<512, 512, 0, stream>>>(ao, wbf + 3145728ull, out);
}